// Round 8
// baseline (490.666 us; speedup 1.0000x reference)
//
#include <hip/hip_runtime.h>
#include <stdint.h>

// Problem constants (LlamaAttention: B=2, S=2048, HID=2048, H=16, KH=4, D=128)
#define Bc   2
#define Sc   2048
#define HIDc 2048
#define Hc   16
#define KHc  4
#define Dc   128
#define HDc  2048   // H*D
#define KHDc 512    // KH*D
#define QKVS 3072   // fused QKV row stride (2048 Q + 512 K + 512 V)
#define SCALE2c 0.12751744657f       // D^-0.5 * log2(e)  (exp2 domain)
#define N_ITEMS 1536                 // 1024 split halves (qt>=16) + 512 shorts

typedef _Float16 f16;
typedef _Float16 f16x2 __attribute__((ext_vector_type(2)));
typedef _Float16 f16x4 __attribute__((ext_vector_type(4)));
typedef _Float16 f16x8 __attribute__((ext_vector_type(8)));
typedef float    f32x4 __attribute__((ext_vector_type(4)));

// async global->LDS DMA, 16B per lane; LDS dest = (wave-uniform) base + lane*16
__device__ __forceinline__ void gl_lds16(const void* g, void* l) {
  __builtin_amdgcn_global_load_lds(
      (const __attribute__((address_space(1))) unsigned int*)g,
      (__attribute__((address_space(3))) unsigned int*)l, 16, 0, 0);
}

// ---------------------------------------------------------------- convert hs (x4 vec) + ctr init
__global__ __launch_bounds__(256) void conv_hs(const float* __restrict__ in,
                                               f16* __restrict__ out,
                                               int* __restrict__ ctr) {
  if (blockIdx.x == 0 && threadIdx.x == 0) *ctr = 0;
  int i = (blockIdx.x * 256 + threadIdx.x) * 4;
  float4 v = *(const float4*)&in[i];
  f16x4 o; o[0] = (f16)v.x; o[1] = (f16)v.y; o[2] = (f16)v.z; o[3] = (f16)v.w;
  *(f16x4*)&out[i] = o;
}

// ---------------------------------------------------------------- all weight transposes+convert
__global__ __launch_bounds__(256) void trw_all(const float* __restrict__ wq,
                                               const float* __restrict__ wk,
                                               const float* __restrict__ wv,
                                               const float* __restrict__ wo,
                                               f16* __restrict__ wqkvT,
                                               f16* __restrict__ woT) {
  const int z = blockIdx.z;
  const float* in; f16* out; int C, rowOff;
  if (z == 0)      { in = wq; out = wqkvT; C = 2048; rowOff = 0; }
  else if (z == 1) { in = wk; out = wqkvT; C = 512;  rowOff = 2048; }
  else if (z == 2) { in = wv; out = wqkvT; C = 512;  rowOff = 2560; }
  else             { in = wo; out = woT;   C = 2048; rowOff = 0; }
  if (blockIdx.x * 64 >= C) return;
  __shared__ float Ld[64 * 65];
  const int tid = threadIdx.x;
  const int r0 = blockIdx.y * 64, c0 = blockIdx.x * 64;
#pragma unroll
  for (int p = 0; p < 4; ++p) {
    int idx = p * 256 + tid;
    int r = idx >> 4, c4 = (idx & 15) * 4;
    float4 v = *(const float4*)&in[(size_t)(r0 + r) * C + c0 + c4];
    Ld[r * 65 + c4 + 0] = v.x; Ld[r * 65 + c4 + 1] = v.y;
    Ld[r * 65 + c4 + 2] = v.z; Ld[r * 65 + c4 + 3] = v.w;
  }
  __syncthreads();
#pragma unroll
  for (int p = 0; p < 4; ++p) {
    int idx = p * 256 + tid;
    int oc = idx >> 4, m4 = (idx & 15) * 4;
    f16x4 o;
#pragma unroll
    for (int i = 0; i < 4; ++i) o[i] = (f16)Ld[(m4 + i) * 65 + oc];
    *(f16x4*)&out[(size_t)(rowOff + c0 + oc) * 2048 + r0 + m4] = o;
  }
}

// ---------------------------------------------------------------- V transpose
__global__ __launch_bounds__(256) void v_tr(const f16* __restrict__ QKV,
                                            f16* __restrict__ Vt) {
  __shared__ f16 Ld[64 * 78];
  const int tid = threadIdx.x;
  const int s0 = blockIdx.x * 64, d0 = blockIdx.y * 64;
  const int b = blockIdx.z >> 2, kh = blockIdx.z & 3;
#pragma unroll
  for (int p = 0; p < 2; ++p) {
    int idx = p * 256 + tid;
    int sl = idx >> 3, dc8 = (idx & 7) * 8;
    f16x8 v = *(const f16x8*)&QKV[(size_t)(b * Sc + s0 + sl) * QKVS + 2560 + kh * 128 + d0 + dc8];
#pragma unroll
    for (int i = 0; i < 4; ++i) {
      f16x2 w; w[0] = v[2 * i]; w[1] = v[2 * i + 1];
      *(f16x2*)&Ld[sl * 78 + dc8 + 2 * i] = w;
    }
  }
  __syncthreads();
  {
    int dr = (tid >> 3) * 2, sc8 = (tid & 7) * 8;
    f16x8 r0v, r1v;
#pragma unroll
    for (int j = 0; j < 8; ++j) {
      f16x2 w = *(const f16x2*)&Ld[(sc8 + j) * 78 + dr];
      r0v[j] = w[0]; r1v[j] = w[1];
    }
    size_t obase = ((size_t)(b * KHc + kh) * 128 + d0 + dr) * Sc + s0 + sc8;
    *(f16x8*)&Vt[obase]      = r0v;
    *(f16x8*)&Vt[obase + Sc] = r1v;
  }
}

// ---------------------------------------------------------------- GEMM: C = A @ Bt^T (generic)
__global__ __launch_bounds__(256) void gemm_bt(const f16* __restrict__ A,
                                               const f16* __restrict__ Bt,
                                               void* __restrict__ Cout,
                                               int M, int N, int K, int c_f16) {
  __shared__ f16 Al[128 * 64];
  __shared__ f16 Bl[128 * 64];
  const int tid  = threadIdx.x;
  const int lane = tid & 63, wave = tid >> 6;
  const int quad = lane >> 4, l16 = lane & 15;
  const int wm = (wave >> 1) * 64, wn = (wave & 1) * 64;
  const int m0 = blockIdx.y * 128, n0 = blockIdx.x * 128;
  f32x4 acc[4][4] = {};

  for (int k0 = 0; k0 < K; k0 += 64) {
    __syncthreads();
#pragma unroll
    for (int p = 0; p < 4; ++p) {
      const int g  = wave * 2 + (p >> 1);
      const int kq = (p & 1) * 4 + quad;
      gl_lds16(&A [(size_t)(m0 + g * 16 + l16) * K + k0 + kq * 8], &Al[(wave * 4 + p) * 512]);
      gl_lds16(&Bt[(size_t)(n0 + g * 16 + l16) * K + k0 + kq * 8], &Bl[(wave * 4 + p) * 512]);
    }
    __syncthreads();
#pragma unroll
    for (int ks = 0; ks < 2; ++ks) {
      f16x8 af[4], bf[4];
#pragma unroll
      for (int i = 0; i < 4; ++i)
        af[i] = *(const f16x8*)&Al[((((wave >> 1) * 4 + i) * 8 + ks * 4 + quad) * 16 + l16) * 8];
#pragma unroll
      for (int j = 0; j < 4; ++j)
        bf[j] = *(const f16x8*)&Bl[((((wave & 1) * 4 + j) * 8 + ks * 4 + quad) * 16 + l16) * 8];
#pragma unroll
      for (int i = 0; i < 4; ++i)
#pragma unroll
        for (int j = 0; j < 4; ++j)
          acc[i][j] = __builtin_amdgcn_mfma_f32_16x16x32_f16(af[i], bf[j], acc[i][j], 0, 0, 0);
    }
  }

  if (c_f16) {
    f16* C = (f16*)Cout;
#pragma unroll
    for (int i = 0; i < 4; ++i)
#pragma unroll
      for (int j = 0; j < 4; ++j)
#pragma unroll
        for (int r = 0; r < 4; ++r)
          C[(size_t)(m0 + wm + i * 16 + quad * 4 + r) * N + n0 + wn + j * 16 + l16] =
              (f16)acc[i][j][r];
  } else {
    float* C = (float*)Cout;
#pragma unroll
    for (int i = 0; i < 4; ++i)
#pragma unroll
      for (int j = 0; j < 4; ++j)
#pragma unroll
        for (int r = 0; r < 4; ++r)
          C[(size_t)(m0 + wm + i * 16 + quad * 4 + r) * N + n0 + wn + j * 16 + l16] =
              acc[i][j][r];
  }
}

// ---------------------------------------------------------------- QKV GEMM + fused RoPE epilogue
// Same K-loop as gemm_bt, but each wave's B column-groups are remapped to
// {w32..w32+31} U {w32+64..w32+95} (w32=(wave&1)*32) so RoPE pairs (d, d+64)
// land in acc frags j and j+2 of the SAME lane. B LDS addr = g*1024 + kq*128
// + l16*8 (g = 16-col group, kq = ks*4+quad) — identical to gemm_bt's layout,
// only the g index changes. n-tiles: 0..15 = Q heads, 16..19 = K kv-heads
// (roped), 20..23 = V (plain).
__global__ __launch_bounds__(256) void gemm_qkv(const f16* __restrict__ A,
                                                const f16* __restrict__ Bt,
                                                f16* __restrict__ C,
                                                const float* __restrict__ cosb,
                                                const float* __restrict__ sinb) {
  __shared__ f16 Al[128 * 64];
  __shared__ f16 Bl[128 * 64];
  const int tid  = threadIdx.x;
  const int lane = tid & 63, wave = tid >> 6;
  const int quad = lane >> 4, l16 = lane & 15;
  const int wm = (wave >> 1) * 64;
  const int m0 = blockIdx.y * 128, n0 = blockIdx.x * 128;
  const int K = 2048;
  f32x4 acc[4][4] = {};

  for (int k0 = 0; k0 < K; k0 += 64) {
    __syncthreads();
#pragma unroll
    for (int p = 0; p < 4; ++p) {
      const int g  = wave * 2 + (p >> 1);
      const int kq = (p & 1) * 4 + quad;
      gl_lds16(&A [(size_t)(m0 + g * 16 + l16) * K + k0 + kq * 8], &Al[(wave * 4 + p) * 512]);
      gl_lds16(&Bt[(size_t)(n0 + g * 16 + l16) * K + k0 + kq * 8], &Bl[(wave * 4 + p) * 512]);
    }
    __syncthreads();
#pragma unroll
    for (int ks = 0; ks < 2; ++ks) {
      f16x8 af[4], bf[4];
#pragma unroll
      for (int i = 0; i < 4; ++i)
        af[i] = *(const f16x8*)&Al[((((wave >> 1) * 4 + i) * 8 + ks * 4 + quad) * 16 + l16) * 8];
#pragma unroll
      for (int j = 0; j < 4; ++j) {
        const int g = (wave & 1) * 2 + (j & 1) + ((j >> 1) << 2);  // remapped col-group
        bf[j] = *(const f16x8*)&Bl[((g * 8 + ks * 4 + quad) * 16 + l16) * 8];  // FIX: g*8, was g*128
      }
#pragma unroll
      for (int i = 0; i < 4; ++i)
#pragma unroll
        for (int j = 0; j < 4; ++j)
          acc[i][j] = __builtin_amdgcn_mfma_f32_16x16x32_f16(af[i], bf[j], acc[i][j], 0, 0, 0);
    }
  }

  // ---- fused RoPE on Q (tiles 0..15) and K (16..19); d = (wave&1)*32 + {0,16} + l16
  if (blockIdx.x < 20) {
    const int d0 = (wave & 1) * 32 + l16;
#pragma unroll
    for (int i = 0; i < 4; ++i)
#pragma unroll
      for (int r = 0; r < 4; ++r) {
        const int row = m0 + wm + i * 16 + quad * 4 + r;
        const float* cp = cosb + (size_t)row * 128;
        const float* sp = sinb + (size_t)row * 128;
        float c0 = cp[d0], s0 = sp[d0], c1 = cp[d0 + 16], s1 = sp[d0 + 16];
        float x0 = acc[i][0][r], x2 = acc[i][2][r];
        float x1 = acc[i][1][r], x3 = acc[i][3][r];
        acc[i][0][r] = x0 * c0 - x2 * s0;
        acc[i][2][r] = x2 * c0 + x0 * s0;
        acc[i][1][r] = x1 * c1 - x3 * s1;
        acc[i][3][r] = x3 * c1 + x1 * s1;
      }
  }

#pragma unroll
  for (int j = 0; j < 4; ++j) {
    const int g = (wave & 1) * 2 + (j & 1) + ((j >> 1) << 2);
    const int col = n0 + g * 16 + l16;
#pragma unroll
    for (int i = 0; i < 4; ++i)
#pragma unroll
      for (int r = 0; r < 4; ++r)
        C[(size_t)(m0 + wm + i * 16 + quad * 4 + r) * QKVS + col] = (f16)acc[i][j][r];
  }
}

// ---------------------------------------------------------------- fused causal attention v4
// Split-K work items (qt>=16 tiles split in two K-halves -> 1536 items, cost
// 8.5..16.5 units; cost-descending queue over 1024 blocks). Row-sums via MFMA
// ones-fragment; exp2 domain. Halves write normalized partial O + (m,l) to ws.
__global__ __launch_bounds__(256, 4) void attn_v4(const f16* __restrict__ QKV,
                                                  const f16* __restrict__ Vt,
                                                  f16* __restrict__ Ob,
                                                  f16* __restrict__ Opart,
                                                  float2* __restrict__ ML,
                                                  int* __restrict__ ctr) {
  __shared__ f16 Kl[64 * 128];
  __shared__ f16 Vl[64 * 128];
  __shared__ f16 Ps[4 * 512];    // per-wave 16x32 P tile: w*512+(col>>3)*128+row*8+(col&7)
  __shared__ int item_s;
  const int tid  = threadIdx.x;
  const int lane = tid & 63, wave = tid >> 6;
  const int quad = lane >> 4, l16 = lane & 15;

  // ones B-fragment: col 0 = 1 -> MFMA accumulates P row-sums into C col 0
  f16x8 ones_f;
#pragma unroll
  for (int i = 0; i < 8; ++i) ones_f[i] = (l16 == 0) ? (f16)1.0f : (f16)0.0f;

  for (;;) {
    if (tid == 0) item_s = atomicAdd(ctr, 1);
    __syncthreads();
    const int item = item_s;
    if (item >= N_ITEMS) break;

    // ---- cost-descending item map: bands c=32..17 (halves qt=c-1 x64;
    // shorts qt=c/2-1 x32 when c even), then shorts qt=7..0.
    int qt, bh, k0t, k1t, hf = -1;
    if (item < 1280) {
      int base = 0, c = 32;
#pragma unroll 1
      for (; c >= 17; --c) {
        int sz = (c & 1) ? 64 : 96;
        if (item < base + sz) break;
        base += sz;
      }
      int off = item - base;
      if (off < 64) {
        qt = c - 1; hf = off >> 5; bh = off & 31;
        int nk = qt + 1, hn = nk >> 1;
        k0t = hf ? hn : 0; k1t = hf ? nk : hn;
      } else {
        qt = (c >> 1) - 1; bh = off - 64; k0t = 0; k1t = qt + 1;
      }
    } else {
      int off = item - 1280;
      qt = 7 - (off >> 5); bh = off & 31; k0t = 0; k1t = qt + 1;
    }
    const int b = bh >> 4, h = bh & 15, kh = h >> 2;
    const int qbase = qt * 64 + wave * 16;

    f16x8 qf[4];
    {
      const f16* qp = QKV + (size_t)(b * Sc + qbase + l16) * QKVS + h * 128 + quad * 8;
#pragma unroll
      for (int c = 0; c < 4; ++c) qf[c] = *(const f16x8*)(qp + c * 32);
    }
    float m_i[4] = {-1e30f, -1e30f, -1e30f, -1e30f};
    f32x4 ls = {};
    f32x4 o[8] = {};

    for (int kt = k0t; kt < k1t; ++kt) {
      __syncthreads();  // prior iteration's LDS reads done
#pragma unroll
      for (int p = 0; p < 4; ++p) {
        gl_lds16(&QKV[(size_t)(b * Sc + kt * 64 + wave * 16 + l16) * QKVS + 2048 + kh * 128 + p * 32 + quad * 8],
                 &Kl[(wave * 4 + p) * 512]);
        const int dt = wave * 2 + (p >> 1), kc = p & 1;
        gl_lds16(&Vt[(size_t)((b * KHc + kh) * 128 + dt * 16 + l16) * Sc + kt * 64 + kc * 32 + quad * 8],
                 &Vl[(wave * 4 + p) * 512]);
      }
      __syncthreads();  // barrier drains vmcnt -> DMA visible

      // ---- scores for all 4 16-col groups
      f32x4 s[4] = {};
#pragma unroll
      for (int kc = 0; kc < 2; ++kc)
#pragma unroll
        for (int c = 0; c < 4; ++c) {
          f16x8 ka = *(const f16x8*)&Kl[(((kc * 2 + 0) * 4 + c) * 4 + quad) * 128 + l16 * 8];
          f16x8 kb = *(const f16x8*)&Kl[(((kc * 2 + 1) * 4 + c) * 4 + quad) * 128 + l16 * 8];
          s[kc * 2 + 0] = __builtin_amdgcn_mfma_f32_16x16x32_f16(qf[c], ka, s[kc * 2 + 0], 0, 0, 0);
          s[kc * 2 + 1] = __builtin_amdgcn_mfma_f32_16x16x32_f16(qf[c], kb, s[kc * 2 + 1], 0, 0, 0);
        }

      // ---- single softmax pass (exp2 domain; sums via MFMA)
      const int cb = kt * 64 + l16;
      const int wb = wave * 512 + (l16 & 7);
      const int rhi = l16 >> 3;
      float e2[4], e3[4], alpha[4];
#pragma unroll
      for (int r = 0; r < 4; ++r) {
        int qrow = qbase + quad * 4 + r;
        float v0 = s[0][r] * SCALE2c, v1 = s[1][r] * SCALE2c;
        float v2 = s[2][r] * SCALE2c, v3 = s[3][r] * SCALE2c;
        if (cb      > qrow) v0 = -1e30f;
        if (cb + 16 > qrow) v1 = -1e30f;
        if (cb + 32 > qrow) v2 = -1e30f;
        if (cb + 48 > qrow) v3 = -1e30f;
        float mx = fmaxf(fmaxf(v0, v1), fmaxf(v2, v3));
        mx = fmaxf(mx, __shfl_xor(mx, 1));
        mx = fmaxf(mx, __shfl_xor(mx, 2));
        mx = fmaxf(mx, __shfl_xor(mx, 4));
        mx = fmaxf(mx, __shfl_xor(mx, 8));
        float mnew = fmaxf(m_i[r], mx);
        alpha[r] = exp2f(m_i[r] - mnew);
        m_i[r] = mnew;
        v0 = exp2f(v0 - mnew); v1 = exp2f(v1 - mnew);
        v2 = exp2f(v2 - mnew); v3 = exp2f(v3 - mnew);
        int rowoff = (quad * 4 + r) * 8;
        Ps[wb + (rhi + 0) * 128 + rowoff] = (f16)v0;
        Ps[wb + (rhi + 2) * 128 + rowoff] = (f16)v1;
        e2[r] = v2; e3[r] = v3;
      }
#pragma unroll
      for (int r = 0; r < 4; ++r) ls[r] *= alpha[r];
#pragma unroll
      for (int dt = 0; dt < 8; ++dt)
#pragma unroll
        for (int r = 0; r < 4; ++r) o[dt][r] *= alpha[r];

      // ---- PV chunk kc=0 (cols 0..31) + row-sum MFMA
      {
        f16x8 pf = *(const f16x8*)&Ps[wave * 512 + quad * 128 + l16 * 8];
        ls = __builtin_amdgcn_mfma_f32_16x16x32_f16(pf, ones_f, ls, 0, 0, 0);
#pragma unroll
        for (int dt = 0; dt < 8; ++dt) {
          f16x8 vf = *(const f16x8*)&Vl[((dt * 2 + 0) * 4 + quad) * 128 + l16 * 8];
          o[dt] = __builtin_amdgcn_mfma_f32_16x16x32_f16(pf, vf, o[dt], 0, 0, 0);
        }
      }
      // ---- PV chunk kc=1 (cols 32..63); wave-local DS in-order -> WAR-safe
#pragma unroll
      for (int r = 0; r < 4; ++r) {
        int rowoff = (quad * 4 + r) * 8;
        Ps[wb + (rhi + 0) * 128 + rowoff] = (f16)e2[r];
        Ps[wb + (rhi + 2) * 128 + rowoff] = (f16)e3[r];
      }
      {
        f16x8 pf = *(const f16x8*)&Ps[wave * 512 + quad * 128 + l16 * 8];
        ls = __builtin_amdgcn_mfma_f32_16x16x32_f16(pf, ones_f, ls, 0, 0, 0);
#pragma unroll
        for (int dt = 0; dt < 8; ++dt) {
          f16x8 vf = *(const f16x8*)&Vl[((dt * 2 + 1) * 4 + quad) * 128 + l16 * 8];
          o[dt] = __builtin_amdgcn_mfma_f32_16x16x32_f16(pf, vf, o[dt], 0, 0, 0);
        }
      }
    }

    // ---- epilogue: l lives in lanes l16==0 (C col 0); broadcast within quad
    float inv[4], lrow[4];
#pragma unroll
    for (int r = 0; r < 4; ++r) {
      lrow[r] = __shfl(ls[r], lane & 48);
      inv[r] = 1.0f / lrow[r];
    }
    if (hf < 0) {
#pragma unroll
      for (int dt = 0; dt < 8; ++dt)
#pragma unroll
        for (int r = 0; r < 4; ++r)
          Ob[(size_t)(b * Sc + qbase + quad * 4 + r) * HDc + h * 128 + dt * 16 + l16] =
              (f16)(o[dt][r] * inv[r]);
    } else {
      const int tile = (qt - 16) * 32 + bh;
      f16* op = Opart + ((size_t)tile * 2 + hf) * (64 * 128);
#pragma unroll
      for (int dt = 0; dt < 8; ++dt)
#pragma unroll
        for (int r = 0; r < 4; ++r)
          op[(wave * 16 + quad * 4 + r) * 128 + dt * 16 + l16] = (f16)(o[dt][r] * inv[r]);
      if (l16 == 0) {
#pragma unroll
        for (int r = 0; r < 4; ++r) {
          float2 ml; ml.x = m_i[r]; ml.y = lrow[r];
          ML[((size_t)tile * 2 + hf) * 64 + wave * 16 + quad * 4 + r] = ml;
        }
      }
    }
  }
}

// ---------------------------------------------------------------- merge split-K halves
__global__ __launch_bounds__(256) void attn_merge(const f16* __restrict__ Opart,
                                                  const float2* __restrict__ ML,
                                                  f16* __restrict__ Ob) {
  const int tile = blockIdx.x;
  const int qt = 16 + (tile >> 5), bh = tile & 31;
  const int b = bh >> 4, h = bh & 15;
  const int tid = threadIdx.x;
  const int row = tid >> 2, c0 = (tid & 3) * 32;
  float2 ml1 = ML[(size_t)tile * 2 * 64 + row];
  float2 ml2 = ML[((size_t)tile * 2 + 1) * 64 + row];
  float m = fmaxf(ml1.x, ml2.x);
  float w1 = ml1.y * exp2f(ml1.x - m);
  float w2 = ml2.y * exp2f(ml2.x - m);
  float rinv = 1.0f / (w1 + w2);
  float a1 = w1 * rinv, a2 = w2 * rinv;
  const f16* o1 = Opart + (size_t)tile * 2 * (64 * 128) + row * 128 + c0;
  const f16* o2 = o1 + 64 * 128;
  f16* out = Ob + (size_t)(b * Sc + qt * 64 + row) * HDc + h * 128 + c0;
#pragma unroll
  for (int j = 0; j < 4; ++j) {
    f16x8 x1 = *(const f16x8*)(o1 + j * 8);
    f16x8 x2 = *(const f16x8*)(o2 + j * 8);
    f16x8 y;
#pragma unroll
    for (int i = 0; i < 8; ++i) y[i] = (f16)(a1 * (float)x1[i] + a2 * (float)x2[i]);
    *(f16x8*)(out + j * 8) = y;
  }
}

// ---------------------------------------------------------------- launch
extern "C" void kernel_launch(void* const* d_in, const int* in_sizes, int n_in,
                              void* d_out, int out_size, void* d_ws, size_t ws_size,
                              hipStream_t stream) {
  (void)in_sizes; (void)n_in; (void)out_size; (void)ws_size;
  const float* hs   = (const float*)d_in[0];
  const float* cosb = (const float*)d_in[1];
  const float* sinb = (const float*)d_in[2];
  // d_in[3] = attention_mask: pure causal, in-kernel.
  const float* wq = (const float*)d_in[4];
  const float* wk = (const float*)d_in[5];
  const float* wv = (const float*)d_in[6];
  const float* wo = (const float*)d_in[7];
  float* out = (float*)d_out;

  char* ws = (char*)d_ws;
  int*  ctr = (int*)ws;
  size_t off = 256;
  auto alloc = [&](size_t bytes) { char* p = ws + off; off += (bytes + 255) & ~(size_t)255; return p; };
  f16*  hsF   = (f16*)alloc((size_t)Bc * Sc * HIDc * 2);      // 16.8 MB (reused as attn out)
  f16*  woT   = (f16*)alloc((size_t)HIDc * HDc * 2);          //  8.4 MB
  f16*  QKVf  = (f16*)alloc((size_t)Bc * Sc * QKVS * 2);      // 25.2 MB
  f16*  Vt_g  = (f16*)alloc((size_t)Bc * KHc * Dc * Sc * 2);  //  4.2 MB
  f16*  wqkvT = (f16*)alloc((size_t)QKVS * HIDc * 2);         // 12.6 MB (dead after QKV GEMM)
  // Opart aliases wqkvT (16.8 MB needs 12.6 + 4.2 fresh tail)
  f16*  Opart = wqkvT;
  {
    size_t opart_bytes = (size_t)512 * 2 * 64 * 128 * 2;      // 16.8 MB
    size_t wqkvT_bytes = (size_t)QKVS * HIDc * 2;
    if (opart_bytes > wqkvT_bytes) off += opart_bytes - wqkvT_bytes;
  }
  float2* ML = (float2*)alloc((size_t)512 * 2 * 64 * sizeof(float2));  // 0.5 MB
  f16*  attnF = hsF;   // hsF dead after QKV GEMM

  conv_hs<<<8192, 256, 0, stream>>>(hs, hsF, ctr);
  trw_all<<<dim3(32, 32, 4), 256, 0, stream>>>(wq, wk, wv, wo, wqkvT, woT);

  gemm_qkv<<<dim3(24, 32), 256, 0, stream>>>(hsF, wqkvT, QKVf, cosb, sinb);

  v_tr<<<dim3(32, 2, 8), 256, 0, stream>>>(QKVf, Vt_g);

  attn_v4<<<1024, 256, 0, stream>>>(QKVf, Vt_g, attnF, Opart, ML, ctr);
  attn_merge<<<512, 256, 0, stream>>>(Opart, ML, attnF);

  gemm_bt<<<dim3(16, 32), 256, 0, stream>>>(attnF, woT, out, 4096, 2048, 2048, 0);
}

// Round 9
// 440.512 us; speedup vs baseline: 1.1139x; 1.1139x over previous
//
#include <hip/hip_runtime.h>
#include <stdint.h>

// Problem constants (LlamaAttention: B=2, S=2048, HID=2048, H=16, KH=4, D=128)
#define Bc   2
#define Sc   2048
#define HIDc 2048
#define Hc   16
#define KHc  4
#define Dc   128
#define HDc  2048   // H*D
#define KHDc 512    // KH*D
#define QKVS 3072   // fused QKV row stride (2048 Q + 512 K + 512 V)
#define SCALE2c 0.12751744657f       // D^-0.5 * log2(e)  (exp2 domain)
#define N_ITEMS 1536                 // 1024 split halves (qt>=16) + 512 shorts

typedef _Float16 f16;
typedef _Float16 f16x2 __attribute__((ext_vector_type(2)));
typedef _Float16 f16x4 __attribute__((ext_vector_type(4)));
typedef _Float16 f16x8 __attribute__((ext_vector_type(8)));
typedef float    f32x4 __attribute__((ext_vector_type(4)));

// async global->LDS DMA, 16B per lane; LDS dest = (wave-uniform) base + lane*16
__device__ __forceinline__ void gl_lds16(const void* g, void* l) {
  __builtin_amdgcn_global_load_lds(
      (const __attribute__((address_space(1))) unsigned int*)g,
      (__attribute__((address_space(3))) unsigned int*)l, 16, 0, 0);
}

// ---------------------------------------------------------------- convert hs (x4 vec) + ctr init
__global__ __launch_bounds__(256) void conv_hs(const float* __restrict__ in,
                                               f16* __restrict__ out,
                                               int* __restrict__ ctr) {
  if (blockIdx.x == 0 && threadIdx.x == 0) *ctr = 0;
  int i = (blockIdx.x * 256 + threadIdx.x) * 4;
  float4 v = *(const float4*)&in[i];
  f16x4 o; o[0] = (f16)v.x; o[1] = (f16)v.y; o[2] = (f16)v.z; o[3] = (f16)v.w;
  *(f16x4*)&out[i] = o;
}

// ---------------------------------------------------------------- all weight transposes+convert
__global__ __launch_bounds__(256) void trw_all(const float* __restrict__ wq,
                                               const float* __restrict__ wk,
                                               const float* __restrict__ wv,
                                               const float* __restrict__ wo,
                                               f16* __restrict__ wqkvT,
                                               f16* __restrict__ woT) {
  const int z = blockIdx.z;
  const float* in; f16* out; int C, rowOff;
  if (z == 0)      { in = wq; out = wqkvT; C = 2048; rowOff = 0; }
  else if (z == 1) { in = wk; out = wqkvT; C = 512;  rowOff = 2048; }
  else if (z == 2) { in = wv; out = wqkvT; C = 512;  rowOff = 2560; }
  else             { in = wo; out = woT;   C = 2048; rowOff = 0; }
  if (blockIdx.x * 64 >= C) return;
  __shared__ float Ld[64 * 65];
  const int tid = threadIdx.x;
  const int r0 = blockIdx.y * 64, c0 = blockIdx.x * 64;
#pragma unroll
  for (int p = 0; p < 4; ++p) {
    int idx = p * 256 + tid;
    int r = idx >> 4, c4 = (idx & 15) * 4;
    float4 v = *(const float4*)&in[(size_t)(r0 + r) * C + c0 + c4];
    Ld[r * 65 + c4 + 0] = v.x; Ld[r * 65 + c4 + 1] = v.y;
    Ld[r * 65 + c4 + 2] = v.z; Ld[r * 65 + c4 + 3] = v.w;
  }
  __syncthreads();
#pragma unroll
  for (int p = 0; p < 4; ++p) {
    int idx = p * 256 + tid;
    int oc = idx >> 4, m4 = (idx & 15) * 4;
    f16x4 o;
#pragma unroll
    for (int i = 0; i < 4; ++i) o[i] = (f16)Ld[(m4 + i) * 65 + oc];
    *(f16x4*)&out[(size_t)(rowOff + c0 + oc) * 2048 + r0 + m4] = o;
  }
}

// ---------------------------------------------------------------- RoPE (Q then K, one kernel)
__global__ __launch_bounds__(256) void rope_all(f16* __restrict__ x,
                                                const float* __restrict__ cb,
                                                const float* __restrict__ sb) {
  int bid = blockIdx.x;
  int colbase, log2h, idx;
  if (bid < 16384) { colbase = 0;    log2h = 4; idx = bid * 256 + threadIdx.x; }
  else             { colbase = 2048; log2h = 2; idx = (bid - 16384) * 256 + threadIdx.x; }
  int d   = idx & 63;
  int h   = (idx >> 6) & ((1 << log2h) - 1);
  int row = idx >> (6 + log2h);
  f16* p = x + (size_t)row * QKVS + colbase + h * 128;
  float x1 = (float)p[d], x2 = (float)p[64 + d];
  float c = cb[(size_t)row * 128 + d], s = sb[(size_t)row * 128 + d];
  p[d]      = (f16)(x1 * c - x2 * s);
  p[64 + d] = (f16)(x2 * c + x1 * s);
}

// ---------------------------------------------------------------- V transpose
__global__ __launch_bounds__(256) void v_tr(const f16* __restrict__ QKV,
                                            f16* __restrict__ Vt) {
  __shared__ f16 Ld[64 * 78];
  const int tid = threadIdx.x;
  const int s0 = blockIdx.x * 64, d0 = blockIdx.y * 64;
  const int b = blockIdx.z >> 2, kh = blockIdx.z & 3;
#pragma unroll
  for (int p = 0; p < 2; ++p) {
    int idx = p * 256 + tid;
    int sl = idx >> 3, dc8 = (idx & 7) * 8;
    f16x8 v = *(const f16x8*)&QKV[(size_t)(b * Sc + s0 + sl) * QKVS + 2560 + kh * 128 + d0 + dc8];
#pragma unroll
    for (int i = 0; i < 4; ++i) {
      f16x2 w; w[0] = v[2 * i]; w[1] = v[2 * i + 1];
      *(f16x2*)&Ld[sl * 78 + dc8 + 2 * i] = w;
    }
  }
  __syncthreads();
  {
    int dr = (tid >> 3) * 2, sc8 = (tid & 7) * 8;
    f16x8 r0v, r1v;
#pragma unroll
    for (int j = 0; j < 8; ++j) {
      f16x2 w = *(const f16x2*)&Ld[(sc8 + j) * 78 + dr];
      r0v[j] = w[0]; r1v[j] = w[1];
    }
    size_t obase = ((size_t)(b * KHc + kh) * 128 + d0 + dr) * Sc + s0 + sc8;
    *(f16x8*)&Vt[obase]      = r0v;
    *(f16x8*)&Vt[obase + Sc] = r1v;
  }
}

// ---------------------------------------------------------------- GEMM: C = A @ Bt^T (generic 128x128)
__global__ __launch_bounds__(256) void gemm_bt(const f16* __restrict__ A,
                                               const f16* __restrict__ Bt,
                                               void* __restrict__ Cout,
                                               int M, int N, int K, int c_f16) {
  __shared__ f16 Al[128 * 64];
  __shared__ f16 Bl[128 * 64];
  const int tid  = threadIdx.x;
  const int lane = tid & 63, wave = tid >> 6;
  const int quad = lane >> 4, l16 = lane & 15;
  const int wm = (wave >> 1) * 64, wn = (wave & 1) * 64;
  const int m0 = blockIdx.y * 128, n0 = blockIdx.x * 128;
  f32x4 acc[4][4] = {};

  for (int k0 = 0; k0 < K; k0 += 64) {
    __syncthreads();
#pragma unroll
    for (int p = 0; p < 4; ++p) {
      const int g  = wave * 2 + (p >> 1);
      const int kq = (p & 1) * 4 + quad;
      gl_lds16(&A [(size_t)(m0 + g * 16 + l16) * K + k0 + kq * 8], &Al[(wave * 4 + p) * 512]);
      gl_lds16(&Bt[(size_t)(n0 + g * 16 + l16) * K + k0 + kq * 8], &Bl[(wave * 4 + p) * 512]);
    }
    __syncthreads();
#pragma unroll
    for (int ks = 0; ks < 2; ++ks) {
      f16x8 af[4], bf[4];
#pragma unroll
      for (int i = 0; i < 4; ++i)
        af[i] = *(const f16x8*)&Al[((((wave >> 1) * 4 + i) * 8 + ks * 4 + quad) * 16 + l16) * 8];
#pragma unroll
      for (int j = 0; j < 4; ++j)
        bf[j] = *(const f16x8*)&Bl[((((wave & 1) * 4 + j) * 8 + ks * 4 + quad) * 16 + l16) * 8];
#pragma unroll
      for (int i = 0; i < 4; ++i)
#pragma unroll
        for (int j = 0; j < 4; ++j)
          acc[i][j] = __builtin_amdgcn_mfma_f32_16x16x32_f16(af[i], bf[j], acc[i][j], 0, 0, 0);
    }
  }

  if (c_f16) {
    f16* C = (f16*)Cout;
#pragma unroll
    for (int i = 0; i < 4; ++i)
#pragma unroll
      for (int j = 0; j < 4; ++j)
#pragma unroll
        for (int r = 0; r < 4; ++r)
          C[(size_t)(m0 + wm + i * 16 + quad * 4 + r) * N + n0 + wn + j * 16 + l16] =
              (f16)acc[i][j][r];
  } else {
    float* C = (float*)Cout;
#pragma unroll
    for (int i = 0; i < 4; ++i)
#pragma unroll
      for (int j = 0; j < 4; ++j)
#pragma unroll
        for (int r = 0; r < 4; ++r)
          C[(size_t)(m0 + wm + i * 16 + quad * 4 + r) * N + n0 + wn + j * 16 + l16] =
              acc[i][j][r];
  }
}

// ---------------------------------------------------------------- QKV GEMM, 128x96 tile
// C(4096,3072) = A(4096,2048) @ Bt(3072,2048)^T, C f16 row stride QKVS.
// 96-col tiles -> grid 32x32 = 1024 blocks = 4 blocks/CU (vs 3 at 128 cols):
// same MFMA work per CU-iter (4blk x 24 = 3blk x 32), +33% resident waves to
// hide the latency wall. Wave = 64 rows x 48 cols (3 col-groups), acc[4][3].
__global__ __launch_bounds__(256) void gemm_qkv96(const f16* __restrict__ A,
                                                  const f16* __restrict__ Bt,
                                                  f16* __restrict__ C) {
  __shared__ f16 Al[128 * 64];  // 16 granules of 512: (g*8+kq)*16+l16 slots
  __shared__ f16 Bl[96 * 64];   // 12 granules of 512
  const int tid  = threadIdx.x;
  const int lane = tid & 63, wave = tid >> 6;
  const int quad = lane >> 4, l16 = lane & 15;
  const int wm = (wave >> 1) * 64;
  const int wnG = (wave & 1) * 3;        // wave's first 16-col group (0 or 3)
  const int m0 = blockIdx.y * 128, n0 = blockIdx.x * 96;
  const int K = 2048;
  f32x4 acc[4][3] = {};

  for (int k0 = 0; k0 < K; k0 += 64) {
    __syncthreads();
#pragma unroll
    for (int p = 0; p < 4; ++p) {      // A: 16 granules, 4 per wave
      const int g  = wave * 2 + (p >> 1);
      const int kq = (p & 1) * 4 + quad;
      gl_lds16(&A[(size_t)(m0 + g * 16 + l16) * K + k0 + kq * 8], &Al[(wave * 4 + p) * 512]);
    }
#pragma unroll
    for (int p = 0; p < 3; ++p) {      // B: 12 granules, 3 per wave
      const int gb = wave * 3 + p;     // granule = gi*2 + khalf
      const int gi = gb >> 1, kh2 = gb & 1;
      gl_lds16(&Bt[(size_t)(n0 + gi * 16 + l16) * K + k0 + kh2 * 32 + quad * 8], &Bl[gb * 512]);
    }
    __syncthreads();
#pragma unroll
    for (int ks = 0; ks < 2; ++ks) {
      f16x8 af[4], bf[3];
#pragma unroll
      for (int i = 0; i < 4; ++i)
        af[i] = *(const f16x8*)&Al[((((wave >> 1) * 4 + i) * 8 + ks * 4 + quad) * 16 + l16) * 8];
#pragma unroll
      for (int j = 0; j < 3; ++j)
        bf[j] = *(const f16x8*)&Bl[(((wnG + j) * 8 + ks * 4 + quad) * 16 + l16) * 8];
#pragma unroll
      for (int i = 0; i < 4; ++i)
#pragma unroll
        for (int j = 0; j < 3; ++j)
          acc[i][j] = __builtin_amdgcn_mfma_f32_16x16x32_f16(af[i], bf[j], acc[i][j], 0, 0, 0);
    }
  }

#pragma unroll
  for (int i = 0; i < 4; ++i)
#pragma unroll
    for (int j = 0; j < 3; ++j)
#pragma unroll
      for (int r = 0; r < 4; ++r)
        C[(size_t)(m0 + wm + i * 16 + quad * 4 + r) * QKVS + n0 + (wnG + j) * 16 + l16] =
            (f16)acc[i][j][r];
}

// ---------------------------------------------------------------- fused causal attention v4
// Split-K work items (qt>=16 tiles split in two K-halves -> 1536 items, cost
// 8.5..16.5 units; cost-descending queue over 1024 blocks). Row-sums via MFMA
// ones-fragment; exp2 domain. Halves write normalized partial O + (m,l) to ws.
__global__ __launch_bounds__(256, 4) void attn_v4(const f16* __restrict__ QKV,
                                                  const f16* __restrict__ Vt,
                                                  f16* __restrict__ Ob,
                                                  f16* __restrict__ Opart,
                                                  float2* __restrict__ ML,
                                                  int* __restrict__ ctr) {
  __shared__ f16 Kl[64 * 128];
  __shared__ f16 Vl[64 * 128];
  __shared__ f16 Ps[4 * 512];    // per-wave 16x32 P tile: w*512+(col>>3)*128+row*8+(col&7)
  __shared__ int item_s;
  const int tid  = threadIdx.x;
  const int lane = tid & 63, wave = tid >> 6;
  const int quad = lane >> 4, l16 = lane & 15;

  // ones B-fragment: col 0 = 1 -> MFMA accumulates P row-sums into C col 0
  f16x8 ones_f;
#pragma unroll
  for (int i = 0; i < 8; ++i) ones_f[i] = (l16 == 0) ? (f16)1.0f : (f16)0.0f;

  for (;;) {
    if (tid == 0) item_s = atomicAdd(ctr, 1);
    __syncthreads();
    const int item = item_s;
    if (item >= N_ITEMS) break;

    // ---- cost-descending item map: bands c=32..17 (halves qt=c-1 x64;
    // shorts qt=c/2-1 x32 when c even), then shorts qt=7..0.
    int qt, bh, k0t, k1t, hf = -1;
    if (item < 1280) {
      int base = 0, c = 32;
#pragma unroll 1
      for (; c >= 17; --c) {
        int sz = (c & 1) ? 64 : 96;
        if (item < base + sz) break;
        base += sz;
      }
      int off = item - base;
      if (off < 64) {
        qt = c - 1; hf = off >> 5; bh = off & 31;
        int nk = qt + 1, hn = nk >> 1;
        k0t = hf ? hn : 0; k1t = hf ? nk : hn;
      } else {
        qt = (c >> 1) - 1; bh = off - 64; k0t = 0; k1t = qt + 1;
      }
    } else {
      int off = item - 1280;
      qt = 7 - (off >> 5); bh = off & 31; k0t = 0; k1t = qt + 1;
    }
    const int b = bh >> 4, h = bh & 15, kh = h >> 2;
    const int qbase = qt * 64 + wave * 16;

    f16x8 qf[4];
    {
      const f16* qp = QKV + (size_t)(b * Sc + qbase + l16) * QKVS + h * 128 + quad * 8;
#pragma unroll
      for (int c = 0; c < 4; ++c) qf[c] = *(const f16x8*)(qp + c * 32);
    }
    float m_i[4] = {-1e30f, -1e30f, -1e30f, -1e30f};
    f32x4 ls = {};
    f32x4 o[8] = {};

    for (int kt = k0t; kt < k1t; ++kt) {
      __syncthreads();  // prior iteration's LDS reads done
#pragma unroll
      for (int p = 0; p < 4; ++p) {
        gl_lds16(&QKV[(size_t)(b * Sc + kt * 64 + wave * 16 + l16) * QKVS + 2048 + kh * 128 + p * 32 + quad * 8],
                 &Kl[(wave * 4 + p) * 512]);
        const int dt = wave * 2 + (p >> 1), kc = p & 1;
        gl_lds16(&Vt[(size_t)((b * KHc + kh) * 128 + dt * 16 + l16) * Sc + kt * 64 + kc * 32 + quad * 8],
                 &Vl[(wave * 4 + p) * 512]);
      }
      __syncthreads();  // barrier drains vmcnt -> DMA visible

      // ---- scores for all 4 16-col groups
      f32x4 s[4] = {};
#pragma unroll
      for (int kc = 0; kc < 2; ++kc)
#pragma unroll
        for (int c = 0; c < 4; ++c) {
          f16x8 ka = *(const f16x8*)&Kl[(((kc * 2 + 0) * 4 + c) * 4 + quad) * 128 + l16 * 8];
          f16x8 kb = *(const f16x8*)&Kl[(((kc * 2 + 1) * 4 + c) * 4 + quad) * 128 + l16 * 8];
          s[kc * 2 + 0] = __builtin_amdgcn_mfma_f32_16x16x32_f16(qf[c], ka, s[kc * 2 + 0], 0, 0, 0);
          s[kc * 2 + 1] = __builtin_amdgcn_mfma_f32_16x16x32_f16(qf[c], kb, s[kc * 2 + 1], 0, 0, 0);
        }

      // ---- single softmax pass (exp2 domain; sums via MFMA)
      const int cb = kt * 64 + l16;
      const int wb = wave * 512 + (l16 & 7);
      const int rhi = l16 >> 3;
      float e2[4], e3[4], alpha[4];
#pragma unroll
      for (int r = 0; r < 4; ++r) {
        int qrow = qbase + quad * 4 + r;
        float v0 = s[0][r] * SCALE2c, v1 = s[1][r] * SCALE2c;
        float v2 = s[2][r] * SCALE2c, v3 = s[3][r] * SCALE2c;
        if (cb      > qrow) v0 = -1e30f;
        if (cb + 16 > qrow) v1 = -1e30f;
        if (cb + 32 > qrow) v2 = -1e30f;
        if (cb + 48 > qrow) v3 = -1e30f;
        float mx = fmaxf(fmaxf(v0, v1), fmaxf(v2, v3));
        mx = fmaxf(mx, __shfl_xor(mx, 1));
        mx = fmaxf(mx, __shfl_xor(mx, 2));
        mx = fmaxf(mx, __shfl_xor(mx, 4));
        mx = fmaxf(mx, __shfl_xor(mx, 8));
        float mnew = fmaxf(m_i[r], mx);
        alpha[r] = exp2f(m_i[r] - mnew);
        m_i[r] = mnew;
        v0 = exp2f(v0 - mnew); v1 = exp2f(v1 - mnew);
        v2 = exp2f(v2 - mnew); v3 = exp2f(v3 - mnew);
        int rowoff = (quad * 4 + r) * 8;
        Ps[wb + (rhi + 0) * 128 + rowoff] = (f16)v0;
        Ps[wb + (rhi + 2) * 128 + rowoff] = (f16)v1;
        e2[r] = v2; e3[r] = v3;
      }
#pragma unroll
      for (int r = 0; r < 4; ++r) ls[r] *= alpha[r];
#pragma unroll
      for (int dt = 0; dt < 8; ++dt)
#pragma unroll
        for (int r = 0; r < 4; ++r) o[dt][r] *= alpha[r];

      // ---- PV chunk kc=0 (cols 0..31) + row-sum MFMA
      {
        f16x8 pf = *(const f16x8*)&Ps[wave * 512 + quad * 128 + l16 * 8];
        ls = __builtin_amdgcn_mfma_f32_16x16x32_f16(pf, ones_f, ls, 0, 0, 0);
#pragma unroll
        for (int dt = 0; dt < 8; ++dt) {
          f16x8 vf = *(const f16x8*)&Vl[((dt * 2 + 0) * 4 + quad) * 128 + l16 * 8];
          o[dt] = __builtin_amdgcn_mfma_f32_16x16x32_f16(pf, vf, o[dt], 0, 0, 0);
        }
      }
      // ---- PV chunk kc=1 (cols 32..63); wave-local DS in-order -> WAR-safe
#pragma unroll
      for (int r = 0; r < 4; ++r) {
        int rowoff = (quad * 4 + r) * 8;
        Ps[wb + (rhi + 0) * 128 + rowoff] = (f16)e2[r];
        Ps[wb + (rhi + 2) * 128 + rowoff] = (f16)e3[r];
      }
      {
        f16x8 pf = *(const f16x8*)&Ps[wave * 512 + quad * 128 + l16 * 8];
        ls = __builtin_amdgcn_mfma_f32_16x16x32_f16(pf, ones_f, ls, 0, 0, 0);
#pragma unroll
        for (int dt = 0; dt < 8; ++dt) {
          f16x8 vf = *(const f16x8*)&Vl[((dt * 2 + 1) * 4 + quad) * 128 + l16 * 8];
          o[dt] = __builtin_amdgcn_mfma_f32_16x16x32_f16(pf, vf, o[dt], 0, 0, 0);
        }
      }
    }

    // ---- epilogue: l lives in lanes l16==0 (C col 0); broadcast within quad
    float inv[4], lrow[4];
#pragma unroll
    for (int r = 0; r < 4; ++r) {
      lrow[r] = __shfl(ls[r], lane & 48);
      inv[r] = 1.0f / lrow[r];
    }
    if (hf < 0) {
#pragma unroll
      for (int dt = 0; dt < 8; ++dt)
#pragma unroll
        for (int r = 0; r < 4; ++r)
          Ob[(size_t)(b * Sc + qbase + quad * 4 + r) * HDc + h * 128 + dt * 16 + l16] =
              (f16)(o[dt][r] * inv[r]);
    } else {
      const int tile = (qt - 16) * 32 + bh;
      f16* op = Opart + ((size_t)tile * 2 + hf) * (64 * 128);
#pragma unroll
      for (int dt = 0; dt < 8; ++dt)
#pragma unroll
        for (int r = 0; r < 4; ++r)
          op[(wave * 16 + quad * 4 + r) * 128 + dt * 16 + l16] = (f16)(o[dt][r] * inv[r]);
      if (l16 == 0) {
#pragma unroll
        for (int r = 0; r < 4; ++r) {
          float2 ml; ml.x = m_i[r]; ml.y = lrow[r];
          ML[((size_t)tile * 2 + hf) * 64 + wave * 16 + quad * 4 + r] = ml;
        }
      }
    }
  }
}

// ---------------------------------------------------------------- merge split-K halves
__global__ __launch_bounds__(256) void attn_merge(const f16* __restrict__ Opart,
                                                  const float2* __restrict__ ML,
                                                  f16* __restrict__ Ob) {
  const int tile = blockIdx.x;
  const int qt = 16 + (tile >> 5), bh = tile & 31;
  const int b = bh >> 4, h = bh & 15;
  const int tid = threadIdx.x;
  const int row = tid >> 2, c0 = (tid & 3) * 32;
  float2 ml1 = ML[(size_t)tile * 2 * 64 + row];
  float2 ml2 = ML[((size_t)tile * 2 + 1) * 64 + row];
  float m = fmaxf(ml1.x, ml2.x);
  float w1 = ml1.y * exp2f(ml1.x - m);
  float w2 = ml2.y * exp2f(ml2.x - m);
  float rinv = 1.0f / (w1 + w2);
  float a1 = w1 * rinv, a2 = w2 * rinv;
  const f16* o1 = Opart + (size_t)tile * 2 * (64 * 128) + row * 128 + c0;
  const f16* o2 = o1 + 64 * 128;
  f16* out = Ob + (size_t)(b * Sc + qt * 64 + row) * HDc + h * 128 + c0;
#pragma unroll
  for (int j = 0; j < 4; ++j) {
    f16x8 x1 = *(const f16x8*)(o1 + j * 8);
    f16x8 x2 = *(const f16x8*)(o2 + j * 8);
    f16x8 y;
#pragma unroll
    for (int i = 0; i < 8; ++i) y[i] = (f16)(a1 * (float)x1[i] + a2 * (float)x2[i]);
    *(f16x8*)(out + j * 8) = y;
  }
}

// ---------------------------------------------------------------- launch
extern "C" void kernel_launch(void* const* d_in, const int* in_sizes, int n_in,
                              void* d_out, int out_size, void* d_ws, size_t ws_size,
                              hipStream_t stream) {
  (void)in_sizes; (void)n_in; (void)out_size; (void)ws_size;
  const float* hs   = (const float*)d_in[0];
  const float* cosb = (const float*)d_in[1];
  const float* sinb = (const float*)d_in[2];
  // d_in[3] = attention_mask: pure causal, in-kernel.
  const float* wq = (const float*)d_in[4];
  const float* wk = (const float*)d_in[5];
  const float* wv = (const float*)d_in[6];
  const float* wo = (const float*)d_in[7];
  float* out = (float*)d_out;

  char* ws = (char*)d_ws;
  int*  ctr = (int*)ws;
  size_t off = 256;
  auto alloc = [&](size_t bytes) { char* p = ws + off; off += (bytes + 255) & ~(size_t)255; return p; };
  f16*  hsF   = (f16*)alloc((size_t)Bc * Sc * HIDc * 2);      // 16.8 MB (reused as attn out)
  f16*  woT   = (f16*)alloc((size_t)HIDc * HDc * 2);          //  8.4 MB
  f16*  QKVf  = (f16*)alloc((size_t)Bc * Sc * QKVS * 2);      // 25.2 MB
  f16*  Vt_g  = (f16*)alloc((size_t)Bc * KHc * Dc * Sc * 2);  //  4.2 MB
  f16*  wqkvT = (f16*)alloc((size_t)QKVS * HIDc * 2);         // 12.6 MB (dead after QKV GEMM)
  // Opart aliases wqkvT (16.8 MB needs 12.6 + 4.2 fresh tail)
  f16*  Opart = wqkvT;
  {
    size_t opart_bytes = (size_t)512 * 2 * 64 * 128 * 2;      // 16.8 MB
    size_t wqkvT_bytes = (size_t)QKVS * HIDc * 2;
    if (opart_bytes > wqkvT_bytes) off += opart_bytes - wqkvT_bytes;
  }
  float2* ML = (float2*)alloc((size_t)512 * 2 * 64 * sizeof(float2));  // 0.5 MB
  f16*  attnF = hsF;   // hsF dead after QKV GEMM

  conv_hs<<<8192, 256, 0, stream>>>(hs, hsF, ctr);
  trw_all<<<dim3(32, 32, 4), 256, 0, stream>>>(wq, wk, wv, wo, wqkvT, woT);

  gemm_qkv96<<<dim3(32, 32), 256, 0, stream>>>(hsF, wqkvT, QKVf);

  rope_all<<<20480, 256, 0, stream>>>(QKVf, cosb, sinb);
  v_tr<<<dim3(32, 2, 8), 256, 0, stream>>>(QKVf, Vt_g);

  attn_v4<<<1024, 256, 0, stream>>>(QKVf, Vt_g, attnF, Opart, ML, ctr);
  attn_merge<<<512, 256, 0, stream>>>(Opart, ML, attnF);

  gemm_bt<<<dim3(16, 32), 256, 0, stream>>>(attnF, woT, out, 4096, 2048, 2048, 0);
}